// Round 11
// baseline (156.132 us; speedup 1.0000x reference)
//
#include <hip/hip_runtime.h>
#include <hip/hip_bf16.h>
#include <math.h>

#define BB 2
#define SS 2048
#define HH 16
#define DH 64
#define DQK 128
#define DD (HH*DH)
// Q folded scale = (1/sqrt(128)) * log2(e)  -> scores arrive in log2 domain
#define QS2   0.12751758f
// 8 * log2(e): fixed-max bias in log2 domain (cancels exactly in softmax)
#define EBIAS 11.5415605f
// partial slot pitch in f16 units: 4096 O^T(f16) + 128 (64 f32 l) + 128 pad
#define SLOTP 4352

typedef _Float16 half8_t __attribute__((ext_vector_type(8)));
typedef _Float16 half4_t __attribute__((ext_vector_type(4)));
typedef float f32x4_t __attribute__((ext_vector_type(4)));
typedef float f32x4v __attribute__((ext_vector_type(4)));

// sin/cos in revolution domain: sin(2pi*frac(rev)) == sin(2pi*rev)
__device__ __forceinline__ void fsincos(float th, float* sn, float* cs) {
  float rev = th * 0.15915494309189535f;
  rev -= floorf(rev);
#if __has_builtin(__builtin_amdgcn_sinf) && __has_builtin(__builtin_amdgcn_cosf)
  *sn = __builtin_amdgcn_sinf(rev);
  *cs = __builtin_amdgcn_cosf(rev);
#else
  float ang = rev * 6.283185307179586f;
  *sn = __sinf(ang);
  *cs = __cosf(ang);
#endif
}

__device__ __forceinline__ float frcp(float v) {
#if __has_builtin(__builtin_amdgcn_rcpf)
  return __builtin_amdgcn_rcpf(v);
#else
  return 1.f / v;
#endif
}

// Block per (stile, bh); bi = stile*32 + bh -> XCD = bh%8 matches consumers.
//   Q  row-major [bh][s][128], scale QS2 folded
//   K  swizzled  [bh][ktile64][d8 0..15][key 0..63] 16B units
//   V  swizzled  [bh][ktile64][k8 0..7][dv 0..63]  16B units
__global__ __launch_bounds__(256) void gen_qkv(
    const float* __restrict__ x,
    const float* __restrict__ wq, const float* __restrict__ bq,
    const float* __restrict__ phq,
    const float* __restrict__ wk, const float* __restrict__ bk,
    const float* __restrict__ phk,
    const float* __restrict__ wv, const float* __restrict__ bv,
    _Float16* __restrict__ Qd, _Float16* __restrict__ Kd, _Float16* __restrict__ Vtd)
{
  int stile = blockIdx.x >> 5;
  int bh    = blockIdx.x & 31;
  int b = bh >> 4, h = bh & 15;
  int t = threadIdx.x;
  int sl = t >> 2;
  int dq = (t & 3) << 4;
  int s  = stile * 64 + sl;

  __shared__ _Float16 Vl[64 * 65];

  const float* xr = x + (((size_t)b * SS + s) * HH + h) * DH + dq;
  float tv = (float)s;
  int hd0 = h * DH + dq;
  _Float16 qc[16], qs[16], kc[16], ks[16];
#pragma unroll
  for (int g = 0; g < 4; g++) {
    f32x4v x4  = *(const f32x4v*)(xr + g * 4);
    f32x4v wq4 = *(const f32x4v*)(wq + hd0 + g * 4);
    f32x4v bq4 = *(const f32x4v*)(bq + hd0 + g * 4);
    f32x4v pq4 = *(const f32x4v*)(phq + hd0 + g * 4);
    f32x4v wk4 = *(const f32x4v*)(wk + hd0 + g * 4);
    f32x4v bk4 = *(const f32x4v*)(bk + hd0 + g * 4);
    f32x4v pk4 = *(const f32x4v*)(phk + hd0 + g * 4);
    f32x4v wv4 = *(const f32x4v*)(wv + hd0 + g * 4);
    f32x4v bv4 = *(const f32x4v*)(bv + hd0 + g * 4);
#pragma unroll
    for (int i2 = 0; i2 < 4; i2++) {
      int i = g * 4 + i2;
      float xv = x4[i2];
      {
        float th = xv * frcp(1.f + fabsf(wq4[i2])) + fmaf(tv, pq4[i2], bq4[i2]);
        float sn, cs; fsincos(th, &sn, &cs);
        qc[i] = (_Float16)(cs * QS2);
        qs[i] = (_Float16)(sn * QS2);
      }
      {
        float th = xv * frcp(1.f + fabsf(wk4[i2])) + fmaf(tv, pk4[i2], bk4[i2]);
        float sn, cs; fsincos(th, &sn, &cs);
        kc[i] = (_Float16)cs;
        ks[i] = (_Float16)sn;
      }
      {
        float th = xv * frcp(1.f + fabsf(wv4[i2])) + bv4[i2];
        float sn, cs; fsincos(th, &sn, &cs);
        Vl[(dq + i) * 65 + sl] = (_Float16)(cs + sn);
      }
    }
  }
  size_t qbase = ((size_t)bh * SS + s) * DQK;
#pragma unroll
  for (int i = 0; i < 2; i++) {
    *(half8_t*)(Qd + qbase + dq + i * 8)      = *(half8_t*)(&qc[i * 8]);
    *(half8_t*)(Qd + qbase + DH + dq + i * 8) = *(half8_t*)(&qs[i * 8]);
  }
  {
    size_t ktb = ((size_t)bh * 32 + stile) * 8192;
    int fo0 = (t & 3) * 2;
    *(half8_t*)(Kd + ktb + ((size_t)(fo0    ) * 64 + sl) * 8) = *(half8_t*)(&kc[0]);
    *(half8_t*)(Kd + ktb + ((size_t)(fo0 + 1) * 64 + sl) * 8) = *(half8_t*)(&kc[8]);
    *(half8_t*)(Kd + ktb + ((size_t)(fo0 + 8) * 64 + sl) * 8) = *(half8_t*)(&ks[0]);
    *(half8_t*)(Kd + ktb + ((size_t)(fo0 + 9) * 64 + sl) * 8) = *(half8_t*)(&ks[8]);
  }
  __syncthreads();
#pragma unroll
  for (int i = 0; i < 2; i++) {
    int u = t * 2 + i;
    int dv = u & 63, ku = u >> 6;
    _Float16 tmp[8];
#pragma unroll
    for (int jj = 0; jj < 8; jj++) tmp[jj] = Vl[dv * 65 + ku * 8 + jj];
    *(half8_t*)(Vtd + (((size_t)bh * 32 + stile) * 8 + ku) * 512 + dv * 8) =
        *(half8_t*)tmp;
  }
}

// SPLIT-K flash: 2560 blocks = 80 groups x 32 bh. Each (bh,qt) row's chunks
// are split round-robin over ng = ceil(nch/8) groups (<=8 chunks each) ->
// 10240 waves total (2.5x R10's supply), ~6 blocks/CU resident + backfill.
// gidx banding: qt 0-7: 1 group (gidx 0-7); 8-15: 2 (8-23); 16-23: 3 (24-47);
// 24-31: 4 (48-79). slot = bh*80 + gidx. Dispatch order: big groups first.
// Fixed-max softmax -> partials are pure sums: block writes unnormalized
// O^T (f16 [dv][q]) + l (f32[64]) to its slot; combine kernel finishes.
__global__ __launch_bounds__(256) void flash_attn(
    const _Float16* __restrict__ Qd, const _Float16* __restrict__ Kd,
    const _Float16* __restrict__ Vtd, _Float16* __restrict__ Pd)
{
  int bh = blockIdx.x & 31;          // XCD = bh % 8
  int o_ = blockIdx.x >> 5;          // dispatch order 0..79
  // big-first order: band3 (qt31..24), band0 big-first (qt7..0), band2, band1
  int gidx = (o_ < 32) ? (79 - o_) : ((o_ < 40) ? (39 - o_) : (87 - o_));
  int qt, g, ng, cnt;
  if (gidx >= 48)      { int r = gidx - 48; qt = 24 + (r >> 2); g = r & 3; ng = 4; cnt = (qt + 1 - g + 3) >> 2; }
  else if (gidx >= 24) { int r = gidx - 24; int d3 = (r * 11) >> 5; /* r/3 for r<24 */ qt = 16 + d3; g = r - 3 * d3; ng = 3; cnt = (qt + 1 - g + 2) / 3; }
  else if (gidx >= 8)  { int r = gidx - 8;  qt = 8 + (r >> 1); g = r & 1; ng = 2; cnt = (qt + 1 - g + 1) >> 1; }
  else                 { qt = gidx; g = 0; ng = 1; cnt = qt + 1; }
  int nch = qt + 1;
  int q0 = qt * 64;
  int wave = threadIdx.x >> 6;
  int lane = threadIdx.x & 63;
  int lm = lane & 15, lq = lane >> 4;
  int qh = wave >> 1;
  int kh = wave & 1;

  __shared__ __align__(16) float Of[64 * 68];
  __shared__ __align__(16) float Lf[64];

  const _Float16* Kw = Kd + (size_t)bh * 32 * 8192 +
                       ((size_t)lq * 64 + kh * 32 + lm) * 8;
  const _Float16* Vw = Vtd + (size_t)bh * 32 * 4096 +
                       ((size_t)(kh * 4 + (lq >> 1)) * 64 + lm) * 8 + (lq & 1) * 4;

  const _Float16* Qb = Qd + ((size_t)bh * SS + q0 + qh * 32) * DQK;
  half8_t aq[2][4];
#pragma unroll
  for (int qtl = 0; qtl < 2; qtl++)
#pragma unroll
    for (int c = 0; c < 4; c++)
      aq[qtl][c] = *(const half8_t*)(Qb + (qtl * 16 + lm) * DQK + c * 32 + lq * 8);

  f32x4_t o[4][2];
  float l[2] = {0.f, 0.f};
#pragma unroll
  for (int dt = 0; dt < 4; dt++)
#pragma unroll
    for (int qtl = 0; qtl < 2; qtl++) o[dt][qtl] = (f32x4_t){0.f, 0.f, 0.f, 0.f};

  const f32x4_t cinit = (f32x4_t){-EBIAS, -EBIAS, -EBIAS, -EBIAS};

  for (int i = 0; i < cnt; ++i) {
    int kt = g + i * ng;
    const _Float16* Kc = Kw + (size_t)kt * 8192;
    const _Float16* Vc = Vw + (size_t)kt * 4096;
    int k0 = kt * 64;

    half8_t kf[2][4];
#pragma unroll
    for (int c = 0; c < 4; c++) {
      kf[0][c] = *(const half8_t*)(Kc + (size_t)c * 4 * 64 * 8);
      kf[1][c] = *(const half8_t*)(Kc + (size_t)c * 4 * 64 * 8 + 16 * 8);
    }
    half4_t vr[4][2];
#pragma unroll
    for (int dt = 0; dt < 4; dt++)
#pragma unroll
      for (int kg = 0; kg < 2; kg++)
        vr[dt][kg] = *(const half4_t*)(Vc + ((size_t)kg * 2 * 64 + dt * 16) * 8);

    f32x4_t cST[2][2];
    cST[0][0] = cST[0][1] = cST[1][0] = cST[1][1] = cinit;
#pragma unroll
    for (int c = 0; c < 4; c++) {
      cST[0][0] = __builtin_amdgcn_mfma_f32_16x16x32_f16(kf[0][c], aq[0][c], cST[0][0], 0, 0, 0);
      cST[0][1] = __builtin_amdgcn_mfma_f32_16x16x32_f16(kf[0][c], aq[1][c], cST[0][1], 0, 0, 0);
      cST[1][0] = __builtin_amdgcn_mfma_f32_16x16x32_f16(kf[1][c], aq[0][c], cST[1][0], 0, 0, 0);
      cST[1][1] = __builtin_amdgcn_mfma_f32_16x16x32_f16(kf[1][c], aq[1][c], cST[1][1], 0, 0, 0);
    }

    bool maskit = (kt == nch - 1);
    half4_t pb[2][2];
#pragma unroll
    for (int ktl = 0; ktl < 2; ktl++)
#pragma unroll
      for (int qtl = 0; qtl < 2; qtl++) {
        float pf[4];
#pragma unroll
        for (int r = 0; r < 4; r++) {
          float sv = cST[ktl][qtl][r];
          if (maskit) {
            int key  = k0 + kh * 32 + ktl * 16 + lq * 4 + r;
            int qrow = q0 + qh * 32 + qtl * 16 + lm;
            if (key > qrow) sv = -1e30f;
          }
          pf[r] = __builtin_exp2f(sv);
          l[qtl] += pf[r];
        }
        pb[ktl][qtl] = (half4_t){(_Float16)pf[0], (_Float16)pf[1],
                                 (_Float16)pf[2], (_Float16)pf[3]};
      }

#pragma unroll
    for (int dt = 0; dt < 4; dt++)
#pragma unroll
      for (int kg = 0; kg < 2; kg++) {
        o[dt][0] = __builtin_amdgcn_mfma_f32_16x16x16f16(vr[dt][kg], pb[kg][0], o[dt][0], 0, 0, 0);
        o[dt][1] = __builtin_amdgcn_mfma_f32_16x16x16f16(vr[dt][kg], pb[kg][1], o[dt][1], 0, 0, 0);
      }
  }

  // all lanes end with l summed over keys for q = qtl*16+lm
#pragma unroll
  for (int qtl = 0; qtl < 2; qtl++) {
    l[qtl] += __shfl_xor(l[qtl], 16);
    l[qtl] += __shfl_xor(l[qtl], 32);
  }

  // kh-combine via LDS, then kh=0 stores the unnormalized partial to its slot
  if (kh == 1) {
#pragma unroll
    for (int qtl = 0; qtl < 2; qtl++) {
      int row = qh * 32 + qtl * 16 + lm;
#pragma unroll
      for (int dt = 0; dt < 4; dt++)
#pragma unroll
        for (int r = 0; r < 4; r++)
          Of[row * 68 + dt * 16 + lq * 4 + r] = o[dt][qtl][r];
      if (lq == 0) Lf[row] = l[qtl];
    }
  }
  __syncthreads();
  if (kh == 0) {
    _Float16* sp = Pd + (size_t)(bh * 80 + gidx) * SLOTP;
    float* lp = (float*)(sp + 4096);
#pragma unroll
    for (int qtl = 0; qtl < 2; qtl++) {
      int qg = qh * 32 + qtl * 16 + lm;
#pragma unroll
      for (int dt = 0; dt < 4; dt++)
#pragma unroll
        for (int r = 0; r < 4; r++) {
          int dv = dt * 16 + lq * 4 + r;
          sp[dv * 64 + qg] = (_Float16)(o[dt][qtl][r] + Of[qg * 68 + dv]);
        }
      if (lq == 0) lp[qg] = l[qtl] + Lf[qg];
    }
  }
}

// 1024 blocks = (qt, bh): sum <=4 partials, normalize, sincos epilogue.
// Reads hit the same XCD's L2 (bi%8 = bh%8). LDS transpose for coalesced out.
__global__ __launch_bounds__(256) void combine(
    const _Float16* __restrict__ Pd,
    const float* __restrict__ wout, const float* __restrict__ bout,
    float* __restrict__ out)
{
  int qt = blockIdx.x >> 5;
  int bh = blockIdx.x & 31;
  int b = bh >> 4, hh = bh & 15;
  int band = qt >> 3;
  int ng = band + 1;
  int base = bh * 80 + ((band * (band + 1)) >> 1) * 8 + (qt & 7) * ng;
  int t = threadIdx.x;
  int q = t & 63;
  int dvb = t >> 6;

  float acc[16];
#pragma unroll
  for (int i = 0; i < 16; i++) acc[i] = 0.f;
  float lv = 0.f;
  for (int gi = 0; gi < ng; gi++) {
    const _Float16* sp = Pd + (size_t)(base + gi) * SLOTP;
    lv += ((const float*)(sp + 4096))[q];
#pragma unroll
    for (int i = 0; i < 16; i++)
      acc[i] += (float)sp[(dvb * 16 + i) * 64 + q];
  }
  float rl = frcp(lv);

  __shared__ float Osh[64 * 65];
#pragma unroll
  for (int i = 0; i < 16; i++)
    Osh[q * 65 + dvb * 16 + i] = acc[i] * rl;
  __syncthreads();

  int dv2 = t & 63;
  int dcol = hh * DH + dv2;
  float iw = frcp(1.f + fabsf(wout[dcol]));
  float bo = bout[dcol];
#pragma unroll
  for (int r = 0; r < 16; r++) {
    int qrow = (t >> 6) + r * 4;
    float th = Osh[qrow * 65 + dv2] * iw + bo;
    float sn, cs; fsincos(th, &sn, &cs);
    out[((size_t)b * SS + qt * 64 + qrow) * DD + dcol] = cs + sn;
  }
}

extern "C" void kernel_launch(void* const* d_in, const int* in_sizes, int n_in,
                              void* d_out, int out_size, void* d_ws, size_t ws_size,
                              hipStream_t stream) {
  (void)in_sizes; (void)n_in; (void)out_size; (void)ws_size;
  const float* x   = (const float*)d_in[0];
  const float* wq  = (const float*)d_in[1];
  const float* bq  = (const float*)d_in[2];
  const float* phq = (const float*)d_in[3];
  const float* wk  = (const float*)d_in[4];
  const float* bk  = (const float*)d_in[5];
  const float* phk = (const float*)d_in[6];
  const float* wv  = (const float*)d_in[7];
  const float* bv  = (const float*)d_in[8];
  const float* wo  = (const float*)d_in[9];
  const float* bo  = (const float*)d_in[10];

  _Float16* Qd  = (_Float16*)d_ws;
  _Float16* Kd  = Qd + (size_t)BB * HH * SS * DQK;      // +16 MiB
  _Float16* Vtd = Kd + (size_t)BB * HH * SS * DQK;      // +16 MiB
  _Float16* Pd  = Vtd + (size_t)BB * HH * SS * DH;      // +8 MiB; Pd = 21.3 MiB

  gen_qkv<<<BB * HH * (SS / 64), 256, 0, stream>>>(
      x, wq, bq, phq, wk, bk, phk, wv, bv, Qd, Kd, Vtd);
  flash_attn<<<80 * 32, 256, 0, stream>>>(Qd, Kd, Vtd, Pd);
  combine<<<32 * 32, 256, 0, stream>>>(Pd, wo, bo, (float*)d_out);
}

// Round 12
// 150.164 us; speedup vs baseline: 1.0397x; 1.0397x over previous
//
#include <hip/hip_runtime.h>
#include <hip/hip_bf16.h>
#include <math.h>

#define BB 2
#define SS 2048
#define HH 16
#define DH 64
#define DQK 128
#define DD (HH*DH)
// Q folded scale = (1/sqrt(128)) * log2(e)  -> scores arrive in log2 domain
#define QS2   0.12751758f
// 8 * log2(e): fixed-max bias in log2 domain (cancels exactly in softmax)
#define EBIAS 11.5415605f

typedef _Float16 half8_t __attribute__((ext_vector_type(8)));
typedef _Float16 half4_t __attribute__((ext_vector_type(4)));
typedef float f32x4_t __attribute__((ext_vector_type(4)));
typedef float f32x4v __attribute__((ext_vector_type(4)));

// sin/cos in revolution domain: sin(2pi*frac(rev)) == sin(2pi*rev)
__device__ __forceinline__ void fsincos(float th, float* sn, float* cs) {
  float rev = th * 0.15915494309189535f;
  rev -= floorf(rev);
#if __has_builtin(__builtin_amdgcn_sinf) && __has_builtin(__builtin_amdgcn_cosf)
  *sn = __builtin_amdgcn_sinf(rev);
  *cs = __builtin_amdgcn_cosf(rev);
#else
  float ang = rev * 6.283185307179586f;
  *sn = __sinf(ang);
  *cs = __cosf(ang);
#endif
}

__device__ __forceinline__ float frcp(float v) {
#if __has_builtin(__builtin_amdgcn_rcpf)
  return __builtin_amdgcn_rcpf(v);
#else
  return 1.f / v;
#endif
}

// async global->LDS DMA, 16B/lane, LDS dest = uniform base + lane*16
__device__ __forceinline__ void dma16(const void* g, void* l) {
  __builtin_amdgcn_global_load_lds(
      (const __attribute__((address_space(1))) unsigned int*)g,
      (__attribute__((address_space(3))) unsigned int*)l, 16, 0, 0);
}

// Block per (stile, bh); bi = stile*32 + bh -> XCD = bh%8 matches consumers.
//   Q  row-major [bh][s][128], scale QS2 folded
//   K  swizzled  [bh][ktile64][d8 0..15][key 0..63] 16B units
//   V  swizzled  [bh][ktile64][k8 0..7][dv 0..63]  16B units
__global__ __launch_bounds__(256) void gen_qkv(
    const float* __restrict__ x,
    const float* __restrict__ wq, const float* __restrict__ bq,
    const float* __restrict__ phq,
    const float* __restrict__ wk, const float* __restrict__ bk,
    const float* __restrict__ phk,
    const float* __restrict__ wv, const float* __restrict__ bv,
    _Float16* __restrict__ Qd, _Float16* __restrict__ Kd, _Float16* __restrict__ Vtd)
{
  int stile = blockIdx.x >> 5;
  int bh    = blockIdx.x & 31;
  int b = bh >> 4, h = bh & 15;
  int t = threadIdx.x;
  int sl = t >> 2;
  int dq = (t & 3) << 4;
  int s  = stile * 64 + sl;

  __shared__ _Float16 Vl[64 * 65];

  const float* xr = x + (((size_t)b * SS + s) * HH + h) * DH + dq;
  float tv = (float)s;
  int hd0 = h * DH + dq;
  _Float16 qc[16], qs[16], kc[16], ks[16];
#pragma unroll
  for (int g = 0; g < 4; g++) {
    f32x4v x4  = *(const f32x4v*)(xr + g * 4);
    f32x4v wq4 = *(const f32x4v*)(wq + hd0 + g * 4);
    f32x4v bq4 = *(const f32x4v*)(bq + hd0 + g * 4);
    f32x4v pq4 = *(const f32x4v*)(phq + hd0 + g * 4);
    f32x4v wk4 = *(const f32x4v*)(wk + hd0 + g * 4);
    f32x4v bk4 = *(const f32x4v*)(bk + hd0 + g * 4);
    f32x4v pk4 = *(const f32x4v*)(phk + hd0 + g * 4);
    f32x4v wv4 = *(const f32x4v*)(wv + hd0 + g * 4);
    f32x4v bv4 = *(const f32x4v*)(bv + hd0 + g * 4);
#pragma unroll
    for (int i2 = 0; i2 < 4; i2++) {
      int i = g * 4 + i2;
      float xv = x4[i2];
      {
        float th = xv * frcp(1.f + fabsf(wq4[i2])) + fmaf(tv, pq4[i2], bq4[i2]);
        float sn, cs; fsincos(th, &sn, &cs);
        qc[i] = (_Float16)(cs * QS2);
        qs[i] = (_Float16)(sn * QS2);
      }
      {
        float th = xv * frcp(1.f + fabsf(wk4[i2])) + fmaf(tv, pk4[i2], bk4[i2]);
        float sn, cs; fsincos(th, &sn, &cs);
        kc[i] = (_Float16)cs;
        ks[i] = (_Float16)sn;
      }
      {
        float th = xv * frcp(1.f + fabsf(wv4[i2])) + bv4[i2];
        float sn, cs; fsincos(th, &sn, &cs);
        Vl[(dq + i) * 65 + sl] = (_Float16)(cs + sn);
      }
    }
  }
  size_t qbase = ((size_t)bh * SS + s) * DQK;
#pragma unroll
  for (int i = 0; i < 2; i++) {
    *(half8_t*)(Qd + qbase + dq + i * 8)      = *(half8_t*)(&qc[i * 8]);
    *(half8_t*)(Qd + qbase + DH + dq + i * 8) = *(half8_t*)(&qs[i * 8]);
  }
  {
    size_t ktb = ((size_t)bh * 32 + stile) * 8192;
    int fo0 = (t & 3) * 2;
    *(half8_t*)(Kd + ktb + ((size_t)(fo0    ) * 64 + sl) * 8) = *(half8_t*)(&kc[0]);
    *(half8_t*)(Kd + ktb + ((size_t)(fo0 + 1) * 64 + sl) * 8) = *(half8_t*)(&kc[8]);
    *(half8_t*)(Kd + ktb + ((size_t)(fo0 + 8) * 64 + sl) * 8) = *(half8_t*)(&ks[0]);
    *(half8_t*)(Kd + ktb + ((size_t)(fo0 + 9) * 64 + sl) * 8) = *(half8_t*)(&ks[8]);
  }
  __syncthreads();
#pragma unroll
  for (int i = 0; i < 2; i++) {
    int u = t * 2 + i;
    int dv = u & 63, ku = u >> 6;
    _Float16 tmp[8];
#pragma unroll
    for (int jj = 0; jj < 8; jj++) tmp[jj] = Vl[dv * 65 + ku * 8 + jj];
    *(half8_t*)(Vtd + (((size_t)bh * 32 + stile) * 8 + ku) * 512 + dv * 8) =
        *(half8_t*)tmp;
  }
}

// 512 blocks x 512 threads: (qtile of 128 rows, bh). Whole grid co-resident
// (2 blocks/CU); qt order 15..8,0..7 pairs big with complementary small per CU
// (~34 chunks/CU uniform) and dispatches big-first. 8 waves = (qh 0..3: 32-q
// quarter) x (kh 0..1: 32-key half). R8 engine: K+V chunk DMA->LDS dbuf
// (24KB/buf), transposed-S (S^T = mfma(K,Q), acc preloaded to -EBIAS), exp2
// in-register, P stays in registers as 16x16x16 PV B-frags. Each 24KB chunk
// now feeds 128 q-rows (2x R8) -> DMA traffic halved. Waves predicate away
// their fully-masked final chunk. Epilogue overlays the KV LDS.
__global__ __launch_bounds__(512) void flash_attn(
    const _Float16* __restrict__ Qd, const _Float16* __restrict__ Kd,
    const _Float16* __restrict__ Vtd,
    const float* __restrict__ wout, const float* __restrict__ bout,
    float* __restrict__ out)
{
  int o_ = blockIdx.x >> 5;
  int qt = (o_ < 8) ? (15 - o_) : (o_ - 8);   // big-first + complementary pairing
  int bh = blockIdx.x & 31;                   // XCD = bh % 8
  int b  = bh >> 4, hh = bh & 15;
  int nch = 2 * qt + 2;
  int q0 = qt * 128;
  int wave = threadIdx.x >> 6;
  int lane = threadIdx.x & 63;
  int lm = lane & 15, lq = lane >> 4;
  int qh = wave >> 1;                         // 0..3
  int kh = wave & 1;

  __shared__ __align__(16) _Float16 KV[2][12288];   // per buf: K 16KB + V 8KB

  const _Float16* Kg = Kd + (size_t)bh * 32 * 8192;
  const _Float16* Vg = Vtd + (size_t)bh * 32 * 4096;

  {  // preload chunk 0 -> buf 0: 16 K-units + 8 V-units; wave w: K{2w,2w+1}, V{w}
#pragma unroll
    for (int i = 0; i < 2; i++)
      dma16(Kg + (size_t)(wave * 2 + i) * 512 + lane * 8, &KV[0][(wave * 2 + i) * 512]);
    dma16(Vg + (size_t)wave * 512 + lane * 8, &KV[0][8192 + wave * 512]);
  }

  // Q B-frags resident: B[n=q][k=c*32+lq*8+j]
  const _Float16* Qb = Qd + ((size_t)bh * SS + q0 + qh * 32) * DQK;
  half8_t aq[2][4];
#pragma unroll
  for (int qtl = 0; qtl < 2; qtl++)
#pragma unroll
    for (int c = 0; c < 4; c++)
      aq[qtl][c] = *(const half8_t*)(Qb + (qtl * 16 + lm) * DQK + c * 32 + lq * 8);

  f32x4_t o[4][2];   // [dv-tile][q-tile], element = O^T[dt*16+lq*4+r][qtl*16+lm]
  float l[2] = {0.f, 0.f};
#pragma unroll
  for (int dt = 0; dt < 4; dt++)
#pragma unroll
    for (int qtl = 0; qtl < 2; qtl++) o[dt][qtl] = (f32x4_t){0.f, 0.f, 0.f, 0.f};

  const f32x4_t cinit = (f32x4_t){-EBIAS, -EBIAS, -EBIAS, -EBIAS};
  int qtop = q0 + qh * 32;   // this wave's lowest q-row

  for (int kt = 0; kt < nch; ++kt) {
    int bf = kt & 1;
    __syncthreads();   // DMA(kt) visible; compute(kt-1) done before buf reuse
    if (kt + 1 < nch) {
      int nb = (kt + 1) & 1;
      const _Float16* gK = Kg + (size_t)(kt + 1) * 8192;
      const _Float16* gV = Vg + (size_t)(kt + 1) * 4096;
#pragma unroll
      for (int i = 0; i < 2; i++)
        dma16(gK + (size_t)(wave * 2 + i) * 512 + lane * 8, &KV[nb][(wave * 2 + i) * 512]);
      dma16(gV + (size_t)wave * 512 + lane * 8, &KV[nb][8192 + wave * 512]);
    }

    int k0 = kt * 64;
    if (k0 > qtop + 31) continue;   // fully-masked for this wave (barriers stay uniform)

    const _Float16* lK = &KV[bf][0];
    const _Float16* lV = &KV[bf][8192];

    // S^T - EBIAS = K Q^T + (-EBIAS) : C-layout (key = lq*4+r, q = lm)
    f32x4_t cST[2][2];
    cST[0][0] = cST[0][1] = cST[1][0] = cST[1][1] = cinit;
#pragma unroll
    for (int c = 0; c < 4; c++) {
      half8_t k0f = *(const half8_t*)(lK + ((size_t)(c * 4 + lq) * 64 + kh * 32 + lm) * 8);
      half8_t k1f = *(const half8_t*)(lK + ((size_t)(c * 4 + lq) * 64 + kh * 32 + 16 + lm) * 8);
      cST[0][0] = __builtin_amdgcn_mfma_f32_16x16x32_f16(k0f, aq[0][c], cST[0][0], 0, 0, 0);
      cST[0][1] = __builtin_amdgcn_mfma_f32_16x16x32_f16(k0f, aq[1][c], cST[0][1], 0, 0, 0);
      cST[1][0] = __builtin_amdgcn_mfma_f32_16x16x32_f16(k1f, aq[0][c], cST[1][0], 0, 0, 0);
      cST[1][1] = __builtin_amdgcn_mfma_f32_16x16x32_f16(k1f, aq[1][c], cST[1][1], 0, 0, 0);
    }

    // p = 2^s in-register; pack -> B-frags (B[n=q=lm][k=lq*4+i])
    bool maskit = (k0 + 63 > qtop);
    half4_t pb[2][2];
#pragma unroll
    for (int ktl = 0; ktl < 2; ktl++)
#pragma unroll
      for (int qtl = 0; qtl < 2; qtl++) {
        float pf[4];
#pragma unroll
        for (int r = 0; r < 4; r++) {
          float sv = cST[ktl][qtl][r];
          if (maskit) {
            int key  = k0 + kh * 32 + ktl * 16 + lq * 4 + r;
            int qrow = qtop + qtl * 16 + lm;
            if (key > qrow) sv = -1e30f;
          }
          pf[r] = __builtin_exp2f(sv);
          l[qtl] += pf[r];
        }
        pb[ktl][qtl] = (half4_t){(_Float16)pf[0], (_Float16)pf[1],
                                 (_Float16)pf[2], (_Float16)pf[3]};
      }

    // O^T += V^T P^T : A = V^T frag (m=dv, k=key lq*4+i), 16 MFMA 16x16x16
#pragma unroll
    for (int dt = 0; dt < 4; dt++)
#pragma unroll
      for (int kg = 0; kg < 2; kg++) {
        half4_t vf = *(const half4_t*)(lV +
            ((size_t)(kh * 4 + kg * 2 + (lq >> 1)) * 64 + dt * 16 + lm) * 8 + (lq & 1) * 4);
        o[dt][0] = __builtin_amdgcn_mfma_f32_16x16x16f16(vf, pb[kg][0], o[dt][0], 0, 0, 0);
        o[dt][1] = __builtin_amdgcn_mfma_f32_16x16x16f16(vf, pb[kg][1], o[dt][1], 0, 0, 0);
      }
  }

  // l summed over keys for q = qtl*16+lm (reduce over lq groups)
#pragma unroll
  for (int qtl = 0; qtl < 2; qtl++) {
    l[qtl] += __shfl_xor(l[qtl], 16);
    l[qtl] += __shfl_xor(l[qtl], 32);
  }

  // kh-combine + normalize via LDS overlay (all K/V reads done), then epilogue
  float* Of = (float*)&KV[0][0];   // [row 0..127][pitch 68] = 34816B < 49152B
  float* Lf = Of + 128 * 68;
  __syncthreads();
  if (kh == 1) {
#pragma unroll
    for (int qtl = 0; qtl < 2; qtl++) {
      int row = qh * 32 + qtl * 16 + lm;
#pragma unroll
      for (int dt = 0; dt < 4; dt++)
#pragma unroll
        for (int r = 0; r < 4; r++)
          Of[row * 68 + dt * 16 + lq * 4 + r] = o[dt][qtl][r];
      if (lq == 0) Lf[row] = l[qtl];
    }
  }
  __syncthreads();
  if (kh == 0) {
#pragma unroll
    for (int qtl = 0; qtl < 2; qtl++) {
      int row = qh * 32 + qtl * 16 + lm;
      float rl = frcp(l[qtl] + Lf[row]);
#pragma unroll
      for (int dt = 0; dt < 4; dt++)
#pragma unroll
        for (int r = 0; r < 4; r++) {
          int idx = row * 68 + dt * 16 + lq * 4 + r;
          Of[idx] = (o[dt][qtl][r] + Of[idx]) * rl;
        }
    }
  }
  __syncthreads();
  {
    int dcol = hh * DH + lane;
    float iw = frcp(1.f + fabsf(wout[dcol]));
    float bo = bout[dcol];
#pragma unroll
    for (int rr = 0; rr < 16; rr++) {
      int row = wave * 16 + rr;
      float th = Of[row * 68 + lane] * iw + bo;
      float sn, cs; fsincos(th, &sn, &cs);
      out[((size_t)b * SS + q0 + row) * DD + dcol] = cs + sn;
    }
  }
}

extern "C" void kernel_launch(void* const* d_in, const int* in_sizes, int n_in,
                              void* d_out, int out_size, void* d_ws, size_t ws_size,
                              hipStream_t stream) {
  (void)in_sizes; (void)n_in; (void)out_size; (void)ws_size;
  const float* x   = (const float*)d_in[0];
  const float* wq  = (const float*)d_in[1];
  const float* bq  = (const float*)d_in[2];
  const float* phq = (const float*)d_in[3];
  const float* wk  = (const float*)d_in[4];
  const float* bk  = (const float*)d_in[5];
  const float* phk = (const float*)d_in[6];
  const float* wv  = (const float*)d_in[7];
  const float* bv  = (const float*)d_in[8];
  const float* wo  = (const float*)d_in[9];
  const float* bo  = (const float*)d_in[10];

  _Float16* Qd  = (_Float16*)d_ws;
  _Float16* Kd  = Qd + (size_t)BB * HH * SS * DQK;
  _Float16* Vtd = Kd + (size_t)BB * HH * SS * DQK;

  gen_qkv<<<BB * HH * (SS / 64), 256, 0, stream>>>(
      x, wq, bq, phq, wk, bk, phk, wv, bv, Qd, Kd, Vtd);
  flash_attn<<<16 * 32, 512, 0, stream>>>(
      Qd, Kd, Vtd, wo, bo, (float*)d_out);
}